// Round 1
// baseline (174.276 us; speedup 1.0000x reference)
//
#include <hip/hip_runtime.h>

#define SRATE 44100.0
#define WIN 16
#define NWIN 4                        // windows per 64-sample chunk
#define STRIDE 17                     // LDS row stride (bank-conflict-free)
#define NBLK 1024                     // 262144 chunks / 256
#define BLK_PER_CH 128

#ifndef M_PI
#define M_PI 3.14159265358979323846
#endif

struct CoefD { double b0, b1, b2, a1, a2; };

__device__ void cascade_step_d(const CoefD* cf, double* s, double x) {
    double u = x;
    #pragma unroll
    for (int i = 0; i < 5; i++) {
        double y   = cf[i].b0 * u + s[2*i];
        double s1n = cf[i].b1 * u - cf[i].a1 * y + s[2*i+1];
        double s2n = cf[i].b2 * u - cf[i].a2 * y;
        s[2*i]   = s1n;
        s[2*i+1] = s2n;
        u = y;
    }
}

// K0: coefficients + fp32 matrix powers.
// mats_f[0..799]     : Pd[d] = A^(64*2^d),    d=0..7  (k1 KS levels, k3 binary decomp)
// mats_f[800..1499]  : Qe[e] = A^(16384*2^e), e=0..6  (k2b KS levels)
__global__ __launch_bounds__(128) void k0_setup(const float* __restrict__ eqp,
                                                float* __restrict__ coef_f,
                                                float* __restrict__ mats_f) {
    __shared__ CoefD cf[5];
    __shared__ double M[100];
    int t = threadIdx.x;

    if (t == 0) {
        for (int i = 0; i < 5; i++) {
            double g  = (double)eqp[i*3 + 0];
            double fc = (double)eqp[i*3 + 1];
            double q  = (double)eqp[i*3 + 2];
            double A  = pow(10.0, g / 40.0);
            double w0 = 2.0 * M_PI * (fc / SRATE);
            double al = sin(w0) / (2.0 * q);
            double c  = cos(w0);
            double b0, b1, b2, a0, a1, a2;
            if (i == 0 || i == 4) {
                double sgn = (i == 4) ? 1.0 : -1.0;
                double sA = sqrt(A);
                b0 = A * ((A + 1.0) + sgn * (A - 1.0) * c + 2.0 * sA * al);
                b1 = -2.0 * sgn * A * ((A - 1.0) + sgn * (A + 1.0) * c);
                b2 = A * ((A + 1.0) + sgn * (A - 1.0) * c - 2.0 * sA * al);
                a0 = (A + 1.0) - sgn * (A - 1.0) * c + 2.0 * sA * al;
                a1 = 2.0 * sgn * ((A - 1.0) - sgn * (A + 1.0) * c);
                a2 = (A + 1.0) - sgn * (A - 1.0) * c - 2.0 * sA * al;
            } else {
                b0 = 1.0 + al * A; b1 = -2.0 * c; b2 = 1.0 - al * A;
                a0 = 1.0 + al / A; a1 = -2.0 * c; a2 = 1.0 - al / A;
            }
            cf[i].b0 = b0 / a0; cf[i].b1 = b1 / a0; cf[i].b2 = b2 / a0;
            cf[i].a1 = a1 / a0; cf[i].a2 = a2 / a0;
            coef_f[i*5 + 0] = (float)(b0 / a0);
            coef_f[i*5 + 1] = (float)(b1 / a0);
            coef_f[i*5 + 2] = (float)(b2 / a0);
            coef_f[i*5 + 3] = (float)(a1 / a0);
            coef_f[i*5 + 4] = (float)(a2 / a0);
        }
    }
    __syncthreads();

    if (t < 10) {
        double s[10];
        for (int k = 0; k < 10; k++) s[k] = (k == t) ? 1.0 : 0.0;
        cascade_step_d(cf, s, 0.0);
        for (int r = 0; r < 10; r++) M[r*10 + t] = s[r];
    }
    __syncthreads();

    for (int k = 1; k <= 20; k++) {
        double val = 0.0;
        if (t < 100) {
            int r = t / 10, c = t % 10;
            for (int j = 0; j < 10; j++) val += M[r*10 + j] * M[j*10 + c];
        }
        __syncthreads();
        if (t < 100) {
            M[t] = val;
            if (k >= 6 && k <= 13) mats_f[(k-6)*100 + t]         = (float)val;
            if (k >= 14)           mats_f[800 + (k-14)*100 + t]  = (float)val;
        }
        __syncthreads();
    }
}

// K1 (fused with intra-block scan): zero-state cascade per 64-sample chunk,
// then Kogge-Stone over the block's 256 chunks. LDS staging is single-pass
// double-buffered with ONE barrier per window; scan persona reuses the same LDS.
__global__ __launch_bounds__(256, 4) void k1_fused(const float* __restrict__ x,
                                                   const float* __restrict__ coef,
                                                   const float* __restrict__ mats_f,
                                                   float* __restrict__ ibuf,
                                                   float* __restrict__ abuf) {
    __shared__ union SmemU {
        float stage[2][256 * STRIDE];                    // 34816 B
        struct { float M[800]; float buf[256][11]; } scan; // 14464 B (fits in stage[0])
    } sm;
    int t = threadIdx.x, b = blockIdx.x;

    float cb0[5], cb1[5], cb2[5], ca1[5], ca2[5];
    #pragma unroll
    for (int i = 0; i < 5; i++) {
        cb0[i] = coef[i*5+0]; cb1[i] = coef[i*5+1]; cb2[i] = coef[i*5+2];
        ca1[i] = coef[i*5+3]; ca2[i] = coef[i*5+4];
    }
    const float4* x4 = (const float4*)x;
    const size_t base4 = (size_t)b * 4096;       // block = 16384 samples
    const int cb = t >> 2, q = t & 3;

    // prefetch window 0
    float4 rr[4];
    #pragma unroll
    for (int k = 0; k < 4; k++)
        rr[k] = x4[base4 + (size_t)(cb + 64*k) * 16 + q];
    #pragma unroll
    for (int k = 0; k < 4; k++) {
        int o = (cb + 64*k) * STRIDE + q*4;
        sm.stage[0][o+0] = rr[k].x; sm.stage[0][o+1] = rr[k].y;
        sm.stage[0][o+2] = rr[k].z; sm.stage[0][o+3] = rr[k].w;
    }
    __syncthreads();

    float s[10];
    #pragma unroll
    for (int k = 0; k < 10; k++) s[k] = 0.0f;

    for (int w = 0; w < NWIN; w++) {
        if (w + 1 < NWIN) {
            #pragma unroll
            for (int k = 0; k < 4; k++)
                rr[k] = x4[base4 + (size_t)(cb + 64*k) * 16 + (w+1)*4 + q];
        }
        const float* cur = sm.stage[w & 1] + t * STRIDE;
        #pragma unroll
        for (int i = 0; i < WIN; i++) {
            float u = cur[i];
            #pragma unroll
            for (int st = 0; st < 5; st++) {
                float y  = fmaf(cb0[st], u, s[2*st]);
                float t1 = fmaf(cb1[st], u, s[2*st+1]);
                s[2*st+1] = fmaf(-ca2[st], y, cb2[st] * u);
                s[2*st]   = fmaf(-ca1[st], y, t1);
                u = y;
            }
        }
        if (w + 1 < NWIN) {
            float* nb = sm.stage[(w+1) & 1];
            #pragma unroll
            for (int k = 0; k < 4; k++) {
                int o = (cb + 64*k) * STRIDE + q*4;
                nb[o+0] = rr[k].x; nb[o+1] = rr[k].y;
                nb[o+2] = rr[k].z; nb[o+3] = rr[k].w;
            }
        }
        __syncthreads();
    }

    // ---- scan persona (all waves past last barrier; buf/M disjoint from stage[1]) ----
    for (int i = t; i < 800; i += 256) sm.scan.M[i] = mats_f[i];
    #pragma unroll
    for (int r = 0; r < 10; r++) sm.scan.buf[t][r] = s[r];
    __syncthreads();

    for (int d = 0; d < 8; d++) {
        float nv[10];
        bool act = (t >= (1 << d));
        if (act) {
            int src = t - (1 << d);
            #pragma unroll
            for (int r = 0; r < 10; r++) {
                float acc = s[r];
                #pragma unroll
                for (int k = 0; k < 10; k++)
                    acc = fmaf(sm.scan.M[d*100 + r*10 + k], sm.scan.buf[src][k], acc);
                nv[r] = acc;
            }
        }
        __syncthreads();
        if (act) {
            #pragma unroll
            for (int r = 0; r < 10; r++) { s[r] = nv[r]; sm.scan.buf[t][r] = nv[r]; }
        }
        __syncthreads();
    }

    #pragma unroll
    for (int r = 0; r < 10; r++)
        ibuf[(size_t)b * 2560 + r * 256 + t] = (t > 0) ? sm.scan.buf[t-1][r] : 0.0f;
    if (t == 255) {
        #pragma unroll
        for (int r = 0; r < 10; r++) abuf[b * 10 + r] = s[r];
    }
}

// K2b: per-channel scan of the 128 block aggregates -> exclusive block prefixes.
__global__ __launch_bounds__(128) void k2b_scan(const float* __restrict__ mats_f,
                                                const float* __restrict__ abuf,
                                                float* __restrict__ bbuf) {
    __shared__ float Qds[700];
    __shared__ float buf[128][11];
    int t = threadIdx.x, ch = blockIdx.x;
    int g = ch * 128 + t;

    for (int k = t; k < 700; k += 128) Qds[k] = mats_f[800 + k];

    float v[10];
    #pragma unroll
    for (int r = 0; r < 10; r++) { v[r] = abuf[g * 10 + r]; buf[t][r] = v[r]; }
    __syncthreads();

    for (int e = 0; e < 7; e++) {
        float nv[10];
        bool act = (t >= (1 << e));
        if (act) {
            int src = t - (1 << e);
            #pragma unroll
            for (int r = 0; r < 10; r++) {
                float acc = v[r];
                #pragma unroll
                for (int k = 0; k < 10; k++)
                    acc = fmaf(Qds[e*100 + r*10 + k], buf[src][k], acc);
                nv[r] = acc;
            }
        }
        __syncthreads();
        if (act) {
            #pragma unroll
            for (int r = 0; r < 10; r++) { v[r] = nv[r]; buf[t][r] = nv[r]; }
        }
        __syncthreads();
    }
    #pragma unroll
    for (int r = 0; r < 10; r++)
        bbuf[g * 10 + r] = (t > 0) ? buf[t-1][r] : 0.0f;
}

// K3: true init = ibuf_local + A^(64*t) * bbuf[block]; re-run chunk with output
// written IN PLACE into the consumed staging buffer, then coalesced coop-store.
// One barrier per window.
__global__ __launch_bounds__(256, 4) void k3_final(const float* __restrict__ x,
                                                   const float* __restrict__ coef,
                                                   const float* __restrict__ mats_f,
                                                   const float* __restrict__ ibuf,
                                                   const float* __restrict__ bbuf,
                                                   float* __restrict__ out) {
    __shared__ float inb[2][256 * STRIDE];   // 34816 B
    __shared__ float Mds[800];               //  3200 B
    int t = threadIdx.x, b = blockIdx.x;

    const float4* x4 = (const float4*)x;
    float4* o4 = (float4*)out;
    const size_t base4 = (size_t)b * 4096;
    const int cb = t >> 2, q = t & 3;

    // prefetch window 0 first so loads fly during init math
    float4 rr[4];
    #pragma unroll
    for (int k = 0; k < 4; k++)
        rr[k] = x4[base4 + (size_t)(cb + 64*k) * 16 + q];

    for (int i = t; i < 800; i += 256) Mds[i] = mats_f[i];

    float cb0[5], cb1[5], cb2[5], ca1[5], ca2[5];
    #pragma unroll
    for (int i = 0; i < 5; i++) {
        cb0[i] = coef[i*5+0]; cb1[i] = coef[i*5+1]; cb2[i] = coef[i*5+2];
        ca1[i] = coef[i*5+3]; ca2[i] = coef[i*5+4];
    }

    float s[10];
    #pragma unroll
    for (int r = 0; r < 10; r++)
        s[r] = ibuf[(size_t)b * 2560 + r * 256 + t];
    float v[10];
    #pragma unroll
    for (int r = 0; r < 10; r++) v[r] = bbuf[b * 10 + r];

    #pragma unroll
    for (int k = 0; k < 4; k++) {
        int o = (cb + 64*k) * STRIDE + q*4;
        inb[0][o+0] = rr[k].x; inb[0][o+1] = rr[k].y;
        inb[0][o+2] = rr[k].z; inb[0][o+3] = rr[k].w;
    }
    __syncthreads();   // inb[0] ready AND Mds ready

    // binary decomposition: v = A^(64*t) * Bpre
    for (int d = 0; d < 8; d++) {
        float wv[10];
        #pragma unroll
        for (int r = 0; r < 10; r++) {
            float acc = 0.0f;
            #pragma unroll
            for (int k = 0; k < 10; k++)
                acc = fmaf(Mds[d*100 + r*10 + k], v[k], acc);
            wv[r] = acc;
        }
        bool bit = (t >> d) & 1;
        #pragma unroll
        for (int r = 0; r < 10; r++) v[r] = bit ? wv[r] : v[r];
    }
    #pragma unroll
    for (int r = 0; r < 10; r++) s[r] += v[r];

    for (int w = 0; w < NWIN; w++) {
        if (w + 1 < NWIN) {
            #pragma unroll
            for (int k = 0; k < 4; k++)
                rr[k] = x4[base4 + (size_t)(cb + 64*k) * 16 + (w+1)*4 + q];
        }
        float* cur = inb[w & 1] + t * STRIDE;
        #pragma unroll
        for (int i = 0; i < WIN; i++) {
            float u = cur[i];
            #pragma unroll
            for (int st = 0; st < 5; st++) {
                float y  = fmaf(cb0[st], u, s[2*st]);
                float t1 = fmaf(cb1[st], u, s[2*st+1]);
                s[2*st+1] = fmaf(-ca2[st], y, cb2[st] * u);
                s[2*st]   = fmaf(-ca1[st], y, t1);
                u = y;
            }
            cur[i] = u;          // in-place: lane-local row, no extra buffer
        }
        if (w + 1 < NWIN) {
            float* nb = inb[(w+1) & 1];
            #pragma unroll
            for (int k = 0; k < 4; k++) {
                int o = (cb + 64*k) * STRIDE + q*4;
                nb[o+0] = rr[k].x; nb[o+1] = rr[k].y;
                nb[o+2] = rr[k].z; nb[o+3] = rr[k].w;
            }
        }
        __syncthreads();   // y rows visible to coop-store; next inb ready

        // cooperative coalesced store of window w (reads then next-iter writes
        // hit identical per-lane addresses -> program-order safe)
        const float* sb = inb[w & 1];
        #pragma unroll
        for (int k = 0; k < 4; k++) {
            int o = (cb + 64*k) * STRIDE + q*4;
            float4 ov = make_float4(sb[o+0], sb[o+1], sb[o+2], sb[o+3]);
            o4[base4 + (size_t)(cb + 64*k) * 16 + (size_t)w*4 + q] = ov;
        }
    }
}

extern "C" void kernel_launch(void* const* d_in, const int* in_sizes, int n_in,
                              void* d_out, int out_size, void* d_ws, size_t ws_size,
                              hipStream_t stream) {
    const float* x   = (const float*)d_in[0];
    const float* eqp = (const float*)d_in[1];
    float* out = (float*)d_out;
    char* ws = (char*)d_ws;

    float* coef_f = (float*)ws;                              // 25 floats
    float* mats_f = (float*)(ws + 256);                      // 1500 floats
    float* ibuf   = (float*)(ws + 8192);                     // 1024*2560 floats = 10.49 MB
    float* abuf   = (float*)(ws + 8192 + 10485760);          // 1024*10 floats
    float* bbuf   = (float*)(ws + 8192 + 10485760 + 40960);  // 1024*10 floats

    hipLaunchKernelGGL(k0_setup, dim3(1), dim3(128), 0, stream, eqp, coef_f, mats_f);
    hipLaunchKernelGGL(k1_fused, dim3(NBLK), dim3(256), 0, stream, x, coef_f, mats_f, ibuf, abuf);
    hipLaunchKernelGGL(k2b_scan, dim3(8), dim3(128), 0, stream, mats_f, abuf, bbuf);
    hipLaunchKernelGGL(k3_final, dim3(NBLK), dim3(256), 0, stream,
                       x, coef_f, mats_f, ibuf, bbuf, out);
}

// Round 2
// 173.735 us; speedup vs baseline: 1.0031x; 1.0031x over previous
//
#include <hip/hip_runtime.h>

#define SRATE 44100.0
#define WIN 16
#define NWIN 4                        // windows per 64-sample chunk
#define STRIDE 17                     // LDS row stride (bank-conflict-free)
#define NBLK 1024                     // 262144 chunks / 256
#define BLK_PER_CH 128

#ifndef M_PI
#define M_PI 3.14159265358979323846
#endif

struct CoefD { double b0, b1, b2, a1, a2; };

__device__ void cascade_step_d(const CoefD* cf, double* s, double x) {
    double u = x;
    #pragma unroll
    for (int i = 0; i < 5; i++) {
        double y   = cf[i].b0 * u + s[2*i];
        double s1n = cf[i].b1 * u - cf[i].a1 * y + s[2*i+1];
        double s2n = cf[i].b2 * u - cf[i].a2 * y;
        s[2*i]   = s1n;
        s[2*i+1] = s2n;
        u = y;
    }
}

// K0: coefficients + fp32 matrix powers.
// mats_f[0..799]     : Pd[d] = A^(64*2^d),    d=0..7  (k1 KS levels, k3 binary decomp)
// mats_f[800..1499]  : Qe[e] = A^(16384*2^e), e=0..6  (k3 channel-scan levels)
__global__ __launch_bounds__(128) void k0_setup(const float* __restrict__ eqp,
                                                float* __restrict__ coef_f,
                                                float* __restrict__ mats_f) {
    __shared__ CoefD cf[5];
    __shared__ double M[100];
    int t = threadIdx.x;

    // one thread per filter: transcendentals in parallel
    if (t < 5) {
        int i = t;
        double g  = (double)eqp[i*3 + 0];
        double fc = (double)eqp[i*3 + 1];
        double q  = (double)eqp[i*3 + 2];
        double A  = pow(10.0, g / 40.0);
        double w0 = 2.0 * M_PI * (fc / SRATE);
        double al = sin(w0) / (2.0 * q);
        double c  = cos(w0);
        double b0, b1, b2, a0, a1, a2;
        if (i == 0 || i == 4) {
            double sgn = (i == 4) ? 1.0 : -1.0;
            double sA = sqrt(A);
            b0 = A * ((A + 1.0) + sgn * (A - 1.0) * c + 2.0 * sA * al);
            b1 = -2.0 * sgn * A * ((A - 1.0) + sgn * (A + 1.0) * c);
            b2 = A * ((A + 1.0) + sgn * (A - 1.0) * c - 2.0 * sA * al);
            a0 = (A + 1.0) - sgn * (A - 1.0) * c + 2.0 * sA * al;
            a1 = 2.0 * sgn * ((A - 1.0) - sgn * (A + 1.0) * c);
            a2 = (A + 1.0) - sgn * (A - 1.0) * c - 2.0 * sA * al;
        } else {
            b0 = 1.0 + al * A; b1 = -2.0 * c; b2 = 1.0 - al * A;
            a0 = 1.0 + al / A; a1 = -2.0 * c; a2 = 1.0 - al / A;
        }
        cf[i].b0 = b0 / a0; cf[i].b1 = b1 / a0; cf[i].b2 = b2 / a0;
        cf[i].a1 = a1 / a0; cf[i].a2 = a2 / a0;
        coef_f[i*5 + 0] = (float)(b0 / a0);
        coef_f[i*5 + 1] = (float)(b1 / a0);
        coef_f[i*5 + 2] = (float)(b2 / a0);
        coef_f[i*5 + 3] = (float)(a1 / a0);
        coef_f[i*5 + 4] = (float)(a2 / a0);
    }
    __syncthreads();

    if (t < 10) {
        double s[10];
        for (int k = 0; k < 10; k++) s[k] = (k == t) ? 1.0 : 0.0;
        cascade_step_d(cf, s, 0.0);
        for (int r = 0; r < 10; r++) M[r*10 + t] = s[r];
    }
    __syncthreads();

    for (int k = 1; k <= 20; k++) {
        double val = 0.0;
        if (t < 100) {
            int r = t / 10, c = t % 10;
            for (int j = 0; j < 10; j++) val += M[r*10 + j] * M[j*10 + c];
        }
        __syncthreads();
        if (t < 100) {
            M[t] = val;
            if (k >= 6 && k <= 13) mats_f[(k-6)*100 + t]         = (float)val;
            if (k >= 14)           mats_f[800 + (k-14)*100 + t]  = (float)val;
        }
        __syncthreads();
    }
}

// K1 (fused with intra-block scan): zero-state cascade per 64-sample chunk,
// then Kogge-Stone over the block's 256 chunks. Level matrices are read
// wave-uniform from GLOBAL (scalar-load path) — no LDS matrix traffic.
__global__ __launch_bounds__(256, 4) void k1_fused(const float* __restrict__ x,
                                                   const float* __restrict__ coef,
                                                   const float* __restrict__ mats_f,
                                                   float* __restrict__ ibuf,
                                                   float* __restrict__ abuf) {
    __shared__ union SmemU {
        float stage[2][256 * STRIDE];       // 34816 B
        float buf[256][11];                 // 11264 B (overlays stage[0])
    } sm;
    int t = threadIdx.x, b = blockIdx.x;

    float cb0[5], cb1[5], cb2[5], ca1[5], ca2[5];
    #pragma unroll
    for (int i = 0; i < 5; i++) {
        cb0[i] = coef[i*5+0]; cb1[i] = coef[i*5+1]; cb2[i] = coef[i*5+2];
        ca1[i] = coef[i*5+3]; ca2[i] = coef[i*5+4];
    }
    const float4* x4 = (const float4*)x;
    const size_t base4 = (size_t)b * 4096;       // block = 16384 samples
    const int cb = t >> 2, q = t & 3;

    // prefetch window 0
    float4 rr[4];
    #pragma unroll
    for (int k = 0; k < 4; k++)
        rr[k] = x4[base4 + (size_t)(cb + 64*k) * 16 + q];
    #pragma unroll
    for (int k = 0; k < 4; k++) {
        int o = (cb + 64*k) * STRIDE + q*4;
        sm.stage[0][o+0] = rr[k].x; sm.stage[0][o+1] = rr[k].y;
        sm.stage[0][o+2] = rr[k].z; sm.stage[0][o+3] = rr[k].w;
    }
    __syncthreads();

    float s[10];
    #pragma unroll
    for (int k = 0; k < 10; k++) s[k] = 0.0f;

    for (int w = 0; w < NWIN; w++) {
        if (w + 1 < NWIN) {
            #pragma unroll
            for (int k = 0; k < 4; k++)
                rr[k] = x4[base4 + (size_t)(cb + 64*k) * 16 + (w+1)*4 + q];
        }
        const float* cur = sm.stage[w & 1] + t * STRIDE;
        #pragma unroll
        for (int i = 0; i < WIN; i++) {
            float u = cur[i];
            #pragma unroll
            for (int st = 0; st < 5; st++) {
                float y  = fmaf(cb0[st], u, s[2*st]);
                float t1 = fmaf(cb1[st], u, s[2*st+1]);
                s[2*st+1] = fmaf(-ca2[st], y, cb2[st] * u);
                s[2*st]   = fmaf(-ca1[st], y, t1);
                u = y;
            }
        }
        if (w + 1 < NWIN) {
            float* nb = sm.stage[(w+1) & 1];
            #pragma unroll
            for (int k = 0; k < 4; k++) {
                int o = (cb + 64*k) * STRIDE + q*4;
                nb[o+0] = rr[k].x; nb[o+1] = rr[k].y;
                nb[o+2] = rr[k].z; nb[o+3] = rr[k].w;
            }
        }
        __syncthreads();
    }

    // ---- scan persona (buf overlays stage[0]; all staging reads done) ----
    #pragma unroll
    for (int r = 0; r < 10; r++) sm.buf[t][r] = s[r];
    __syncthreads();

    for (int d = 0; d < 8; d++) {
        const float* __restrict__ Mg = mats_f + d*100;   // wave-uniform -> s_load
        float nv[10];
        bool act = (t >= (1 << d));
        if (act) {
            int src = t - (1 << d);
            float bs[10];
            #pragma unroll
            for (int k = 0; k < 10; k++) bs[k] = sm.buf[src][k];
            #pragma unroll
            for (int r = 0; r < 10; r++) {
                float acc = s[r];
                #pragma unroll
                for (int k = 0; k < 10; k++)
                    acc = fmaf(Mg[r*10 + k], bs[k], acc);
                nv[r] = acc;
            }
        }
        __syncthreads();
        if (act) {
            #pragma unroll
            for (int r = 0; r < 10; r++) { s[r] = nv[r]; sm.buf[t][r] = nv[r]; }
        }
        __syncthreads();
    }

    #pragma unroll
    for (int r = 0; r < 10; r++)
        ibuf[(size_t)b * 2560 + r * 256 + t] = (t > 0) ? sm.buf[t-1][r] : 0.0f;
    if (t == 255) {
        #pragma unroll
        for (int r = 0; r < 10; r++) abuf[b * 10 + r] = s[r];
    }
}

// K3: prologue redundantly scans this channel's 128 block aggregates (replaces
// the old k2b kernel), then true init = ibuf_local + A^(64*t) * Bpre, re-run
// chunk with in-place LDS output and coalesced coop-store.
__global__ __launch_bounds__(256, 4) void k3_final(const float* __restrict__ x,
                                                   const float* __restrict__ coef,
                                                   const float* __restrict__ mats_f,
                                                   const float* __restrict__ ibuf,
                                                   const float* __restrict__ abuf,
                                                   float* __restrict__ out) {
    __shared__ union SmemU {
        float inb[2][256 * STRIDE];                           // 34816 B
        struct { float pad[256 * STRIDE]; float sbuf[128][11]; } scn; // sbuf overlays inb[1]
    } sm;
    int t = threadIdx.x, b = blockIdx.x;
    const int ch = b >> 7;          // channel (128 blocks per channel)
    const int ci = b & 127;         // block index within channel

    const float4* x4 = (const float4*)x;
    float4* o4 = (float4*)out;
    const size_t base4 = (size_t)b * 4096;
    const int cb = t >> 2, q = t & 3;

    // prefetch window 0 first so loads fly during init math
    float4 rr[4];
    #pragma unroll
    for (int k = 0; k < 4; k++)
        rr[k] = x4[base4 + (size_t)(cb + 64*k) * 16 + q];

    float cb0[5], cb1[5], cb2[5], ca1[5], ca2[5];
    #pragma unroll
    for (int i = 0; i < 5; i++) {
        cb0[i] = coef[i*5+0]; cb1[i] = coef[i*5+1]; cb2[i] = coef[i*5+2];
        ca1[i] = coef[i*5+3]; ca2[i] = coef[i*5+4];
    }

    float s[10];
    #pragma unroll
    for (int r = 0; r < 10; r++)
        s[r] = ibuf[(size_t)b * 2560 + r * 256 + t];

    #pragma unroll
    for (int k = 0; k < 4; k++) {
        int o = (cb + 64*k) * STRIDE + q*4;
        sm.inb[0][o+0] = rr[k].x; sm.inb[0][o+1] = rr[k].y;
        sm.inb[0][o+2] = rr[k].z; sm.inb[0][o+3] = rr[k].w;
    }
    // stage this channel's 128 aggregates (1280 floats, coalesced)
    for (int idx = t; idx < 1280; idx += 256)
        sm.scn.sbuf[idx / 10][idx % 10] = abuf[(size_t)ch * 1280 + idx];
    __syncthreads();   // inb[0] + sbuf ready

    // ---- channel scan: KS over 128 aggregates (threads 0..127 active) ----
    float v[10];
    if (t < 128) {
        #pragma unroll
        for (int r = 0; r < 10; r++) v[r] = sm.scn.sbuf[t][r];
    }
    for (int e = 0; e < 7; e++) {
        const float* __restrict__ Qg = mats_f + 800 + e*100;  // wave-uniform
        float nv[10];
        bool act = (t < 128) && (t >= (1 << e));
        if (act) {
            int src = t - (1 << e);
            float bs[10];
            #pragma unroll
            for (int k = 0; k < 10; k++) bs[k] = sm.scn.sbuf[src][k];
            #pragma unroll
            for (int r = 0; r < 10; r++) {
                float acc = v[r];
                #pragma unroll
                for (int k = 0; k < 10; k++)
                    acc = fmaf(Qg[r*10 + k], bs[k], acc);
                nv[r] = acc;
            }
        }
        __syncthreads();
        if (act) {
            #pragma unroll
            for (int r = 0; r < 10; r++) { v[r] = nv[r]; sm.scn.sbuf[t][r] = nv[r]; }
        }
        __syncthreads();
    }

    // block prefix Bpre = inclusive scan at ci-1 (broadcast read)
    float bp[10];
    #pragma unroll
    for (int r = 0; r < 10; r++)
        bp[r] = (ci > 0) ? sm.scn.sbuf[ci-1][r] : 0.0f;
    __syncthreads();   // sbuf reads done before inb[1] (same bytes) is written

    // binary decomposition: bp = A^(64*t) * Bpre  (M from global, scalar path)
    for (int d = 0; d < 8; d++) {
        const float* __restrict__ Mg = mats_f + d*100;
        float wv[10];
        #pragma unroll
        for (int r = 0; r < 10; r++) {
            float acc = 0.0f;
            #pragma unroll
            for (int k = 0; k < 10; k++)
                acc = fmaf(Mg[r*10 + k], bp[k], acc);
            wv[r] = acc;
        }
        bool bit = (t >> d) & 1;
        #pragma unroll
        for (int r = 0; r < 10; r++) bp[r] = bit ? wv[r] : bp[r];
    }
    #pragma unroll
    for (int r = 0; r < 10; r++) s[r] += bp[r];

    for (int w = 0; w < NWIN; w++) {
        if (w + 1 < NWIN) {
            #pragma unroll
            for (int k = 0; k < 4; k++)
                rr[k] = x4[base4 + (size_t)(cb + 64*k) * 16 + (w+1)*4 + q];
        }
        float* cur = sm.inb[w & 1] + t * STRIDE;
        #pragma unroll
        for (int i = 0; i < WIN; i++) {
            float u = cur[i];
            #pragma unroll
            for (int st = 0; st < 5; st++) {
                float y  = fmaf(cb0[st], u, s[2*st]);
                float t1 = fmaf(cb1[st], u, s[2*st+1]);
                s[2*st+1] = fmaf(-ca2[st], y, cb2[st] * u);
                s[2*st]   = fmaf(-ca1[st], y, t1);
                u = y;
            }
            cur[i] = u;          // in-place: lane-local row
        }
        if (w + 1 < NWIN) {
            float* nb = sm.inb[(w+1) & 1];
            #pragma unroll
            for (int k = 0; k < 4; k++) {
                int o = (cb + 64*k) * STRIDE + q*4;
                nb[o+0] = rr[k].x; nb[o+1] = rr[k].y;
                nb[o+2] = rr[k].z; nb[o+3] = rr[k].w;
            }
        }
        __syncthreads();   // y rows visible; next inb ready

        // cooperative coalesced store of window w
        const float* sb = sm.inb[w & 1];
        #pragma unroll
        for (int k = 0; k < 4; k++) {
            int o = (cb + 64*k) * STRIDE + q*4;
            float4 ov = make_float4(sb[o+0], sb[o+1], sb[o+2], sb[o+3]);
            o4[base4 + (size_t)(cb + 64*k) * 16 + (size_t)w*4 + q] = ov;
        }
    }
}

extern "C" void kernel_launch(void* const* d_in, const int* in_sizes, int n_in,
                              void* d_out, int out_size, void* d_ws, size_t ws_size,
                              hipStream_t stream) {
    const float* x   = (const float*)d_in[0];
    const float* eqp = (const float*)d_in[1];
    float* out = (float*)d_out;
    char* ws = (char*)d_ws;

    float* coef_f = (float*)ws;                              // 25 floats
    float* mats_f = (float*)(ws + 256);                      // 1500 floats
    float* ibuf   = (float*)(ws + 8192);                     // 1024*2560 floats = 10.49 MB
    float* abuf   = (float*)(ws + 8192 + 10485760);          // 1024*10 floats

    hipLaunchKernelGGL(k0_setup, dim3(1), dim3(128), 0, stream, eqp, coef_f, mats_f);
    hipLaunchKernelGGL(k1_fused, dim3(NBLK), dim3(256), 0, stream, x, coef_f, mats_f, ibuf, abuf);
    hipLaunchKernelGGL(k3_final, dim3(NBLK), dim3(256), 0, stream,
                       x, coef_f, mats_f, ibuf, abuf, out);
}